// Round 3
// baseline (305.372 us; speedup 1.0000x reference)
//
#include <hip/hip_runtime.h>

// DecoderCBatchNorm, round 3: fully fused, 8 threads per point.
// Gather: lanes 0..7 of a point fetch consecutive float4s of each texel.
// MLP: cross-lane cooperative — each thread owns 4 of 32 channels; activation
// broadcast via __shfl within the 8-lane point group; weights are per-lane
// float4 vector loads (L1-cached) instead of scalar-cache streams.
// 524288 threads = 8192 waves = 8 waves/SIMD (vs 1 for thread-per-point).
// B=16, T=4096, L=4, H=W=128, D=32. Output [B,T] f32.

#define BB 16
#define TT 4096
#define LL 4
#define HH 128
#define WW 128
#define DD 32

__global__ __launch_bounds__(256) void decoder_kernel(
    const float* __restrict__ p,        // [B,T,3]
    const float* __restrict__ c,        // [B,L,H,W,D]
    const float* __restrict__ Cmat,     // [B,L,4,3]
    const float* __restrict__ fc_p_W,   // [3,D]
    const float* __restrict__ fc_p_b,   // [D]
    const float* __restrict__ W0,       // [5,D,D]
    const float* __restrict__ b0,       // [5,D]
    const float* __restrict__ W1,       // [5,D,D]
    const float* __restrict__ b1,       // [5,D]
    const float* __restrict__ fc_out_W, // [D]
    const float* __restrict__ fc_out_b, // [1]
    float* __restrict__ out)            // [B,T]
{
    const int tid  = blockIdx.x * blockDim.x + threadIdx.x;  // 0..524287
    const int t    = tid >> 3;          // point id
    const int dg   = tid & 7;           // channel group (4 channels each)
    const int b    = t >> 12;
    const int lane = threadIdx.x & 63;
    const int gbase = lane & 56;        // first lane of this point's 8-lane group
    const int doff = dg * 4;

    // ------------------------------------------------------------ gather ---
    const float* pp = p + (size_t)t * 3;
    const float px = pp[0], py = pp[1], pz = pp[2];
    const float pm0 = px / 0.55f;
    const float pm1 = py / 0.55f;
    const float pm2 = pz / 0.55f;

    const float interval = (float)(2.0 / 127.0);

    float cf0 = 0.f, cf1 = 0.f, cf2 = 0.f, cf3 = 0.f;

    #pragma unroll
    for (int l = 0; l < LL; ++l) {
        const float* cm = Cmat + (size_t)(b * LL + l) * 12;
        const float c00 = cm[0], c01 = cm[1], c02 = cm[2];
        const float c10 = cm[3], c11 = cm[4], c12 = cm[5];
        const float c30 = cm[9];

        float pr0 = c00 * pm0 + c01 * pm1 + c02 * pm2;
        float pr1 = c10 * pm0 + c11 * pm1 + c12 * pm2;
        const float denom = c30 + 0.05f;
        pr0 = pr0 / denom;
        pr1 = pr1 / denom;

        float xg = (pr0 + 1.0f) / interval;
        float yg = (pr1 + 1.0f) / interval;
        xg = (xg >= 127.0f) ? 126.9f : xg;
        xg = (xg < 0.0f)    ? 0.0f   : xg;
        yg = (yg >= 127.0f) ? 126.9f : yg;
        yg = (yg < 0.0f)    ? 0.0f   : yg;

        const float xl = rintf(xg - 0.5f);
        const float xr = rintf(xg + 0.5f);
        const float yl = rintf(yg - 0.5f);
        const float yh = rintf(yg + 0.5f);
        const int xil = (int)xl, xir = (int)xr, yil = (int)yl, yih = (int)yh;

        const float dx = xr - xg;
        const float dy = yh - yg;
        const float w11 = dx * dy;
        const float w12 = (1.0f - dx) * dy;
        const float w21 = dx * (1.0f - dy);
        const float w22 = (1.0f - dx) * (1.0f - dy);

        const float* plane = c + (size_t)(b * LL + l) * (HH * WW * DD);
        const float4 a  = *(const float4*)(plane + ((size_t)xil * WW + yil) * DD + doff);
        const float4 e  = *(const float4*)(plane + ((size_t)xir * WW + yil) * DD + doff);
        const float4 g  = *(const float4*)(plane + ((size_t)xil * WW + yih) * DD + doff);
        const float4 d4 = *(const float4*)(plane + ((size_t)xir * WW + yih) * DD + doff);

        cf0 += w11 * a.x + w12 * e.x + w21 * g.x + w22 * d4.x;
        cf1 += w11 * a.y + w12 * e.y + w21 * g.y + w22 * d4.y;
        cf2 += w11 * a.z + w12 * e.z + w21 * g.z + w22 * d4.z;
        cf3 += w11 * a.w + w12 * e.w + w21 * g.w + w22 * d4.w;
    }

    // ------------------------------------------------------------ fc_p -----
    const float4 bpv = *(const float4*)(fc_p_b + doff);
    const float4 wp0 = *(const float4*)(fc_p_W + doff);
    const float4 wp1 = *(const float4*)(fc_p_W + DD + doff);
    const float4 wp2 = *(const float4*)(fc_p_W + 2 * DD + doff);

    float n0 = bpv.x + px * wp0.x + py * wp1.x + pz * wp2.x + cf0;
    float n1 = bpv.y + px * wp0.y + py * wp1.y + pz * wp2.y + cf1;
    float n2 = bpv.z + px * wp0.z + py * wp1.z + pz * wp2.z + cf2;
    float n3 = bpv.w + px * wp0.w + py * wp1.w + pz * wp2.w + cf3;

    // ------------------------------------------------------- resnet blocks --
    for (int s = 0; s < 5; ++s) {
        if (s > 0) { n0 += cf0; n1 += cf1; n2 += cf2; n3 += cf3; }

        const float* w0p = W0 + (size_t)s * DD * DD + doff;
        const float* w1p = W1 + (size_t)s * DD * DD + doff;

        // h = b0 + relu(net) @ W0
        const float4 b0v = *(const float4*)(b0 + s * DD + doff);
        float h0 = b0v.x, h1 = b0v.y, h2 = b0v.z, h3 = b0v.w;

        float r0 = fmaxf(n0, 0.f), r1 = fmaxf(n1, 0.f);
        float r2 = fmaxf(n2, 0.f), r3 = fmaxf(n3, 0.f);

        #pragma unroll
        for (int k = 0; k < DD; ++k) {
            float src;
            switch (k & 3) {                // static after unroll
                case 0: src = r0; break;
                case 1: src = r1; break;
                case 2: src = r2; break;
                default: src = r3; break;
            }
            const float xk = __shfl(src, gbase | (k >> 2), 64);
            const float4 wv = *(const float4*)(w0p + k * DD);
            h0 += xk * wv.x; h1 += xk * wv.y; h2 += xk * wv.z; h3 += xk * wv.w;
        }

        // net = net + b1 + relu(h) @ W1
        const float4 b1v = *(const float4*)(b1 + s * DD + doff);
        n0 += b1v.x; n1 += b1v.y; n2 += b1v.z; n3 += b1v.w;

        r0 = fmaxf(h0, 0.f); r1 = fmaxf(h1, 0.f);
        r2 = fmaxf(h2, 0.f); r3 = fmaxf(h3, 0.f);

        #pragma unroll
        for (int k = 0; k < DD; ++k) {
            float src;
            switch (k & 3) {
                case 0: src = r0; break;
                case 1: src = r1; break;
                case 2: src = r2; break;
                default: src = r3; break;
            }
            const float hk = __shfl(src, gbase | (k >> 2), 64);
            const float4 wv = *(const float4*)(w1p + k * DD);
            n0 += hk * wv.x; n1 += hk * wv.y; n2 += hk * wv.z; n3 += hk * wv.w;
        }
    }

    // ------------------------------------------------------------ fc_out ---
    const float4 wo = *(const float4*)(fc_out_W + doff);
    float partial = fmaxf(n0, 0.f) * wo.x;
    partial += fmaxf(n1, 0.f) * wo.y;
    partial += fmaxf(n2, 0.f) * wo.z;
    partial += fmaxf(n3, 0.f) * wo.w;

    // reduce across the 8-lane point group
    partial += __shfl_xor(partial, 1, 64);
    partial += __shfl_xor(partial, 2, 64);
    partial += __shfl_xor(partial, 4, 64);

    if (dg == 0) out[t] = partial + fc_out_b[0];
}

extern "C" void kernel_launch(void* const* d_in, const int* in_sizes, int n_in,
                              void* d_out, int out_size, void* d_ws, size_t ws_size,
                              hipStream_t stream) {
    const float* p        = (const float*)d_in[0];
    // d_in[1] = z  [B,128]  -- unused by the reference
    const float* c        = (const float*)d_in[2];
    const float* Cmat     = (const float*)d_in[3];
    const float* fc_p_W   = (const float*)d_in[4];
    const float* fc_p_b   = (const float*)d_in[5];
    const float* W0       = (const float*)d_in[6];
    const float* b0       = (const float*)d_in[7];
    const float* W1       = (const float*)d_in[8];
    const float* b1       = (const float*)d_in[9];
    const float* fc_out_W = (const float*)d_in[10];
    const float* fc_out_b = (const float*)d_in[11];
    float* out = (float*)d_out;

    const int nthreads = BB * TT * 8;   // 524288
    decoder_kernel<<<nthreads / 256, 256, 0, stream>>>(p, c, Cmat, fc_p_W, fc_p_b,
                                                       W0, b0, W1, b1, fc_out_W, fc_out_b, out);
}

// Round 4
// 261.901 us; speedup vs baseline: 1.1660x; 1.1660x over previous
//
#include <hip/hip_runtime.h>

// DecoderCBatchNorm, round 4: wave = 64 points x 16 channels.
// - Weights stay wave-uniform -> SGPR (scalar pipe) weight loads; inner loop
//   is pure v_fmac with SGPR operand (round-3's per-lane VMEM weight loads and
//   per-k shfl/cndmask are gone).
// - Channel halves of a point live in sibling waves of the same block;
//   activations exchanged via LDS (transposed [ch][pt] layout: 2-way bank
//   aliasing = free), double-buffered, one barrier per matmul.
// - 131072 threads = 2048 waves = 2 waves/SIMD (vs 1 for thread-per-point).
// B=16, T=4096, L=4, H=W=128, D=32. Output [B,T] f32.

#define LL 4
#define HH 128
#define WW 128
#define DD 32

__global__ __launch_bounds__(256) void decoder_kernel(
    const float* __restrict__ p,        // [B,T,3]
    const float* __restrict__ c,        // [B,L,H,W,D]
    const float* __restrict__ Cmat,     // [B,L,4,3]
    const float* __restrict__ fc_p_W,   // [3,D]
    const float* __restrict__ fc_p_b,   // [D]
    const float* __restrict__ W0,       // [5,D,D]
    const float* __restrict__ b0,       // [5,D]
    const float* __restrict__ W1,       // [5,D,D]
    const float* __restrict__ b1,       // [5,D]
    const float* __restrict__ fc_out_W, // [D]
    const float* __restrict__ fc_out_b, // [1]
    float* __restrict__ out)            // [B,T]
{
    // [parity][channel][point]; ch-major so lanes (=points) hit banks
    // lane%32 -> 2-way aliasing (free on wave64).
    __shared__ float xbuf[2][DD][128];

    const int lane = threadIdx.x & 63;
    const int w    = threadIdx.x >> 6;              // wave in block: 0..3
    const int half_u = __builtin_amdgcn_readfirstlane(w & 1);   // channel half
    const int pg_u   = __builtin_amdgcn_readfirstlane(w >> 1);  // point group
    const int jbase  = half_u * 16;                 // my first channel (scalar)
    const int pbase  = 16 - jbase;                  // partner's first channel
    const int pt     = pg_u * 64 + lane;            // local point 0..127
    const int t      = blockIdx.x * 128 + pt;       // global point
    const int b_u    = blockIdx.x >> 5;             // batch (128 pts | 4096)

    // ------------------------------------------------------------ gather ---
    const float* pp = p + (size_t)t * 3;
    const float px = pp[0], py = pp[1], pz = pp[2];
    const float pm0 = px / 0.55f;
    const float pm1 = py / 0.55f;
    const float pm2 = pz / 0.55f;

    const float interval = (float)(2.0 / 127.0);

    float cf[16];
    #pragma unroll
    for (int i = 0; i < 16; ++i) cf[i] = 0.0f;

    #pragma unroll
    for (int l = 0; l < LL; ++l) {
        const float* cm = Cmat + (size_t)(b_u * LL + l) * 12;   // uniform addr
        const float c00 = cm[0], c01 = cm[1], c02 = cm[2];
        const float c10 = cm[3], c11 = cm[4], c12 = cm[5];
        const float c30 = cm[9];

        float pr0 = c00 * pm0 + c01 * pm1 + c02 * pm2;
        float pr1 = c10 * pm0 + c11 * pm1 + c12 * pm2;
        const float denom = c30 + 0.05f;
        pr0 = pr0 / denom;
        pr1 = pr1 / denom;

        float xg = (pr0 + 1.0f) / interval;
        float yg = (pr1 + 1.0f) / interval;
        xg = (xg >= 127.0f) ? 126.9f : xg;
        xg = (xg < 0.0f)    ? 0.0f   : xg;
        yg = (yg >= 127.0f) ? 126.9f : yg;
        yg = (yg < 0.0f)    ? 0.0f   : yg;

        const float xl = rintf(xg - 0.5f);
        const float xr = rintf(xg + 0.5f);
        const float yl = rintf(yg - 0.5f);
        const float yh = rintf(yg + 0.5f);
        const int xil = (int)xl, xir = (int)xr, yil = (int)yl, yih = (int)yh;

        const float dx = xr - xg;
        const float dy = yh - yg;
        const float w11 = dx * dy;
        const float w12 = (1.0f - dx) * dy;
        const float w21 = dx * (1.0f - dy);
        const float w22 = (1.0f - dx) * (1.0f - dy);

        const float* plane = c + (size_t)(b_u * LL + l) * (HH * WW * DD);
        const float* t11 = plane + ((size_t)xil * WW + yil) * DD + jbase;
        const float* t12 = plane + ((size_t)xir * WW + yil) * DD + jbase;
        const float* t21 = plane + ((size_t)xil * WW + yih) * DD + jbase;
        const float* t22 = plane + ((size_t)xir * WW + yih) * DD + jbase;

        #pragma unroll
        for (int q = 0; q < 4; ++q) {
            const float4 a  = *(const float4*)(t11 + 4 * q);
            const float4 e  = *(const float4*)(t12 + 4 * q);
            const float4 g  = *(const float4*)(t21 + 4 * q);
            const float4 d4 = *(const float4*)(t22 + 4 * q);
            cf[4*q + 0] += w11 * a.x + w12 * e.x + w21 * g.x + w22 * d4.x;
            cf[4*q + 1] += w11 * a.y + w12 * e.y + w21 * g.y + w22 * d4.y;
            cf[4*q + 2] += w11 * a.z + w12 * e.z + w21 * g.z + w22 * d4.z;
            cf[4*q + 3] += w11 * a.w + w12 * e.w + w21 * g.w + w22 * d4.w;
        }
    }

    // ------------------------------------------------------------ fc_p -----
    float net[16];
    {
        const float* wb  = fc_p_b + jbase;           // uniform
        const float* wr0 = fc_p_W + jbase;
        const float* wr1 = fc_p_W + DD + jbase;
        const float* wr2 = fc_p_W + 2 * DD + jbase;
        #pragma unroll
        for (int j = 0; j < 16; ++j)
            net[j] = wb[j] + px * wr0[j] + py * wr1[j] + pz * wr2[j] + cf[j];
    }

    // ------------------------------------------------------- resnet blocks --
    for (int s = 0; s < 5; ++s) {
        if (s > 0) {
            #pragma unroll
            for (int j = 0; j < 16; ++j) net[j] += cf[j];
        }
        const float* w0m = W0 + (size_t)s * DD * DD;
        const float* w1m = W1 + (size_t)s * DD * DD;

        // ---- matmul 1: h = b0 + relu(net) @ W0   (exchange parity 0) ----
        float r[16];
        #pragma unroll
        for (int j = 0; j < 16; ++j) r[j] = fmaxf(net[j], 0.0f);
        #pragma unroll
        for (int i = 0; i < 16; ++i) xbuf[0][jbase + i][pt] = r[i];
        __syncthreads();
        float xp[16];
        #pragma unroll
        for (int i = 0; i < 16; ++i) xp[i] = xbuf[0][pbase + i][pt];

        float h[16];
        {
            const float* bb = b0 + s * DD + jbase;   // uniform
            #pragma unroll
            for (int j = 0; j < 16; ++j) h[j] = bb[j];
        }
        #pragma unroll
        for (int i = 0; i < 16; ++i) {               // own-half k's
            const float xk = r[i];
            const float* wr = w0m + (size_t)(jbase + i) * DD + jbase;  // uniform
            #pragma unroll
            for (int j = 0; j < 16; ++j) h[j] += xk * wr[j];
        }
        #pragma unroll
        for (int i = 0; i < 16; ++i) {               // partner-half k's
            const float xk = xp[i];
            const float* wr = w0m + (size_t)(pbase + i) * DD + jbase;  // uniform
            #pragma unroll
            for (int j = 0; j < 16; ++j) h[j] += xk * wr[j];
        }

        // ---- matmul 2: net += b1 + relu(h) @ W1  (exchange parity 1) ----
        {
            const float* bb = b1 + s * DD + jbase;   // uniform
            #pragma unroll
            for (int j = 0; j < 16; ++j) net[j] += bb[j];
        }
        #pragma unroll
        for (int j = 0; j < 16; ++j) r[j] = fmaxf(h[j], 0.0f);
        #pragma unroll
        for (int i = 0; i < 16; ++i) xbuf[1][jbase + i][pt] = r[i];
        __syncthreads();
        #pragma unroll
        for (int i = 0; i < 16; ++i) xp[i] = xbuf[1][pbase + i][pt];

        #pragma unroll
        for (int i = 0; i < 16; ++i) {               // own-half k's
            const float xk = r[i];
            const float* wr = w1m + (size_t)(jbase + i) * DD + jbase;  // uniform
            #pragma unroll
            for (int j = 0; j < 16; ++j) net[j] += xk * wr[j];
        }
        #pragma unroll
        for (int i = 0; i < 16; ++i) {               // partner-half k's
            const float xk = xp[i];
            const float* wr = w1m + (size_t)(pbase + i) * DD + jbase;  // uniform
            #pragma unroll
            for (int j = 0; j < 16; ++j) net[j] += xk * wr[j];
        }
    }

    // ------------------------------------------------------------ fc_out ---
    float partial = 0.0f;
    {
        const float* wo = fc_out_W + jbase;          // uniform
        #pragma unroll
        for (int j = 0; j < 16; ++j) partial += fmaxf(net[j], 0.0f) * wo[j];
    }
    // cross-half reduce via LDS (parity-0 buffer is free: last reads of it
    // completed before the parity-1 barrier of the final block).
    xbuf[0][jbase][pt] = partial;
    __syncthreads();
    if (half_u == 0) {
        out[t] = partial + xbuf[0][16][pt] + fc_out_b[0];
    }
}

extern "C" void kernel_launch(void* const* d_in, const int* in_sizes, int n_in,
                              void* d_out, int out_size, void* d_ws, size_t ws_size,
                              hipStream_t stream) {
    const float* p        = (const float*)d_in[0];
    // d_in[1] = z  [B,128]  -- unused by the reference
    const float* c        = (const float*)d_in[2];
    const float* Cmat     = (const float*)d_in[3];
    const float* fc_p_W   = (const float*)d_in[4];
    const float* fc_p_b   = (const float*)d_in[5];
    const float* W0       = (const float*)d_in[6];
    const float* b0       = (const float*)d_in[7];
    const float* W1       = (const float*)d_in[8];
    const float* b1       = (const float*)d_in[9];
    const float* fc_out_W = (const float*)d_in[10];
    const float* fc_out_b = (const float*)d_in[11];
    float* out = (float*)d_out;

    // 65536 points, 128 points per block (2 point-groups x 2 half-waves)
    const int grid = (16 * 4096) / 128;   // 512 blocks = 2 blocks/CU
    decoder_kernel<<<grid, 256, 0, stream>>>(p, c, Cmat, fc_p_W, fc_p_b,
                                             W0, b0, W1, b1, fc_out_W, fc_out_b, out);
}

// Round 5
// 238.725 us; speedup vs baseline: 1.2792x; 1.0971x over previous
//
#include <hip/hip_runtime.h>

// DecoderCBatchNorm, round 5: split kernels.
// Gather: round-2 verified kernel (8 threads/point, coalesced texel reads).
// MLP: thread-per-point, weights OFF the scalar pipe: per-stage weights are
// loaded coalesced into VGPRs (lane L holds flat elem r*64+L) and broadcast
// via v_readlane_b32 (compile-time reg+lane) -> the 1024-MAC inner loop has
// ZERO memory ops and ZERO waitcnt. SMEM lgkmcnt(0) full-drain stalls
// (out-of-order scalar returns force drain-to-zero) are the suspected 70 us.
// B=16, T=4096, L=4, H=W=128, D=32. Output [B,T] f32.

#define LL 4
#define HH 128
#define WW 128
#define DD 32
#define NPT 65536

__device__ __forceinline__ float bcast(float v, int srclane) {
    return __int_as_float(__builtin_amdgcn_readlane(__float_as_int(v), srclane));
}

// ---------------------------------------------------------------- gather ----
__global__ __launch_bounds__(256) void gather_kernel(
    const float* __restrict__ p,        // [B,T,3]
    const float* __restrict__ c,        // [B,L,H,W,D]
    const float* __restrict__ Cmat,     // [B,L,4,3]
    float4* __restrict__ cf_ws)         // [B*T*8] float4
{
    const int tid = blockIdx.x * blockDim.x + threadIdx.x;  // 0..524287
    const int t  = tid >> 3;
    const int dg = tid & 7;
    const int b  = t >> 12;

    const float* pp = p + (size_t)t * 3;
    const float pm0 = pp[0] / 0.55f;
    const float pm1 = pp[1] / 0.55f;
    const float pm2 = pp[2] / 0.55f;

    const float interval = (float)(2.0 / 127.0);

    float4 acc = make_float4(0.f, 0.f, 0.f, 0.f);

    #pragma unroll
    for (int l = 0; l < LL; ++l) {
        const float* cm = Cmat + (size_t)(b * LL + l) * 12;
        const float c00 = cm[0], c01 = cm[1], c02 = cm[2];
        const float c10 = cm[3], c11 = cm[4], c12 = cm[5];
        const float c30 = cm[9];

        float pr0 = c00 * pm0 + c01 * pm1 + c02 * pm2;
        float pr1 = c10 * pm0 + c11 * pm1 + c12 * pm2;
        const float denom = c30 + 0.05f;
        pr0 = pr0 / denom;
        pr1 = pr1 / denom;

        float xg = (pr0 + 1.0f) / interval;
        float yg = (pr1 + 1.0f) / interval;
        xg = (xg >= 127.0f) ? 126.9f : xg;
        xg = (xg < 0.0f)    ? 0.0f   : xg;
        yg = (yg >= 127.0f) ? 126.9f : yg;
        yg = (yg < 0.0f)    ? 0.0f   : yg;

        const float xl = rintf(xg - 0.5f);
        const float xr = rintf(xg + 0.5f);
        const float yl = rintf(yg - 0.5f);
        const float yh = rintf(yg + 0.5f);
        const int xil = (int)xl, xir = (int)xr, yil = (int)yl, yih = (int)yh;

        const float dx = xr - xg;
        const float dy = yh - yg;
        const float w11 = dx * dy;
        const float w12 = (1.0f - dx) * dy;
        const float w21 = dx * (1.0f - dy);
        const float w22 = (1.0f - dx) * (1.0f - dy);

        const float* plane = c + (size_t)(b * LL + l) * (HH * WW * DD);
        const int doff = dg * 4;
        const float4 a  = *(const float4*)(plane + ((size_t)xil * WW + yil) * DD + doff);
        const float4 e  = *(const float4*)(plane + ((size_t)xir * WW + yil) * DD + doff);
        const float4 g  = *(const float4*)(plane + ((size_t)xil * WW + yih) * DD + doff);
        const float4 d4 = *(const float4*)(plane + ((size_t)xir * WW + yih) * DD + doff);

        acc.x += w11 * a.x + w12 * e.x + w21 * g.x + w22 * d4.x;
        acc.y += w11 * a.y + w12 * e.y + w21 * g.y + w22 * d4.y;
        acc.z += w11 * a.z + w12 * e.z + w21 * g.z + w22 * d4.z;
        acc.w += w11 * a.w + w12 * e.w + w21 * g.w + w22 * d4.w;
    }

    cf_ws[tid] = acc;   // coalesced: 64 lanes x 16 B contiguous
}

// ------------------------------------------------------------------- MLP ----
__global__ __launch_bounds__(256) void mlp_kernel(
    const float* __restrict__ p,        // [B,T,3]
    const float* __restrict__ cf_ws,    // [B*T,32]
    const float* __restrict__ fc_p_W,   // [3,D]
    const float* __restrict__ fc_p_b,   // [D]
    const float* __restrict__ W0,       // [5,D,D]
    const float* __restrict__ b0,       // [5,D]
    const float* __restrict__ W1,       // [5,D,D]
    const float* __restrict__ b1,       // [5,D]
    const float* __restrict__ fc_out_W, // [D]
    const float* __restrict__ fc_out_b, // [1]
    float* __restrict__ out)            // [B,T]
{
    const int t    = blockIdx.x * blockDim.x + threadIdx.x;
    const int lane = threadIdx.x & 63;
    const int j32  = lane & 31;

    const float* pp = p + (size_t)t * 3;
    const float px = pp[0], py = pp[1], pz = pp[2];

    float cf[DD];
    const float4* cfv = (const float4*)(cf_ws + (size_t)t * DD);
    #pragma unroll
    for (int q = 0; q < DD / 4; ++q) {
        const float4 v = cfv[q];
        cf[4*q+0] = v.x; cf[4*q+1] = v.y; cf[4*q+2] = v.z; cf[4*q+3] = v.w;
    }

    // fc_p: small one-time weights; per-lane load + readlane broadcast
    // (keeps even this off the scalar-drain path)
    const float vpb  = fc_p_b[j32];          // lanes 0..31 hold b[j]
    const float vpw0 = fc_p_W[j32];
    const float vpw1 = fc_p_W[DD + j32];
    const float vpw2 = fc_p_W[2 * DD + j32];

    float net[DD];
    #pragma unroll
    for (int j = 0; j < DD; ++j) {
        net[j] = bcast(vpb, j) + px * bcast(vpw0, j) + py * bcast(vpw1, j)
               + pz * bcast(vpw2, j) + cf[j];
    }

    float h[DD];
    for (int s = 0; s < 5; ++s) {
        // stage weights -> VGPRs, coalesced (lane L holds flat elem r*64+L)
        const float* Ws0 = W0 + (size_t)s * DD * DD;
        const float* Ws1 = W1 + (size_t)s * DD * DD;
        float wa[16], wb[16];
        #pragma unroll
        for (int r = 0; r < 16; ++r) wa[r] = Ws0[r * 64 + lane];
        #pragma unroll
        for (int r = 0; r < 16; ++r) wb[r] = Ws1[r * 64 + lane];
        const float vb0 = b0[s * DD + j32];
        const float vb1 = b1[s * DD + j32];

        if (s > 0) {
            #pragma unroll
            for (int j = 0; j < DD; ++j) net[j] += cf[j];
        }

        // ---- h = b0 + relu(net) @ W0 ----
        float r0[DD];
        #pragma unroll
        for (int j = 0; j < DD; ++j) r0[j] = fmaxf(net[j], 0.0f);
        #pragma unroll
        for (int j = 0; j < DD; ++j) h[j] = bcast(vb0, j);
        #pragma unroll
        for (int k = 0; k < DD; ++k) {
            const float xk = r0[k];
            #pragma unroll
            for (int j = 0; j < DD; ++j) {
                const int f = k * DD + j;
                h[j] += xk * bcast(wa[f >> 6], f & 63);
            }
        }

        // ---- net += b1 + relu(h) @ W1 ----
        #pragma unroll
        for (int j = 0; j < DD; ++j) net[j] += bcast(vb1, j);
        #pragma unroll
        for (int j = 0; j < DD; ++j) r0[j] = fmaxf(h[j], 0.0f);
        #pragma unroll
        for (int k = 0; k < DD; ++k) {
            const float xk = r0[k];
            #pragma unroll
            for (int j = 0; j < DD; ++j) {
                const int f = k * DD + j;
                net[j] += xk * bcast(wb[f >> 6], f & 63);
            }
        }
    }

    // fc_out
    const float vwo = fc_out_W[j32];
    float o = fc_out_b[0];
    #pragma unroll
    for (int k = 0; k < DD; ++k) o += fmaxf(net[k], 0.0f) * bcast(vwo, k);
    out[t] = o;
}

// ------------------------------------------------- round-1 fused fallback ---
__global__ __launch_bounds__(256) void decoder_fused_kernel(
    const float* __restrict__ p,
    const float* __restrict__ c,
    const float* __restrict__ Cmat,
    const float* __restrict__ fc_p_W,
    const float* __restrict__ fc_p_b,
    const float* __restrict__ W0,
    const float* __restrict__ b0,
    const float* __restrict__ W1,
    const float* __restrict__ b1,
    const float* __restrict__ fc_out_W,
    const float* __restrict__ fc_out_b,
    float* __restrict__ out)
{
    const int t = blockIdx.x * blockDim.x + threadIdx.x;
    const int b = t >> 12;

    const float* pp = p + (size_t)t * 3;
    const float px = pp[0], py = pp[1], pz = pp[2];
    const float pm0 = px / 0.55f, pm1 = py / 0.55f, pm2 = pz / 0.55f;

    float cf[DD];
    #pragma unroll
    for (int j = 0; j < DD; ++j) cf[j] = 0.0f;
    const float interval = (float)(2.0 / 127.0);

    #pragma unroll
    for (int l = 0; l < LL; ++l) {
        const float* cm = Cmat + (size_t)(b * LL + l) * 12;
        float pr0 = cm[0]*pm0 + cm[1]*pm1 + cm[2]*pm2;
        float pr1 = cm[3]*pm0 + cm[4]*pm1 + cm[5]*pm2;
        const float denom = cm[9] + 0.05f;
        pr0 /= denom; pr1 /= denom;
        float xg = (pr0 + 1.0f) / interval;
        float yg = (pr1 + 1.0f) / interval;
        xg = (xg >= 127.0f) ? 126.9f : xg; xg = (xg < 0.0f) ? 0.0f : xg;
        yg = (yg >= 127.0f) ? 126.9f : yg; yg = (yg < 0.0f) ? 0.0f : yg;
        const float xl = rintf(xg - 0.5f), xr = rintf(xg + 0.5f);
        const float yl = rintf(yg - 0.5f), yh = rintf(yg + 0.5f);
        const int xil = (int)xl, xir = (int)xr, yil = (int)yl, yih = (int)yh;
        const float dx = xr - xg, dy = yh - yg;
        const float w11 = dx*dy, w12 = (1.f-dx)*dy, w21 = dx*(1.f-dy), w22 = (1.f-dx)*(1.f-dy);
        const float* plane = c + (size_t)(b * LL + l) * (HH * WW * DD);
        const float4* f11 = (const float4*)(plane + ((size_t)xil * WW + yil) * DD);
        const float4* f12 = (const float4*)(plane + ((size_t)xir * WW + yil) * DD);
        const float4* f21 = (const float4*)(plane + ((size_t)xil * WW + yih) * DD);
        const float4* f22 = (const float4*)(plane + ((size_t)xir * WW + yih) * DD);
        #pragma unroll
        for (int q = 0; q < DD / 4; ++q) {
            const float4 a = f11[q], e = f12[q], g = f21[q], d4 = f22[q];
            cf[4*q+0] += w11*a.x + w12*e.x + w21*g.x + w22*d4.x;
            cf[4*q+1] += w11*a.y + w12*e.y + w21*g.y + w22*d4.y;
            cf[4*q+2] += w11*a.z + w12*e.z + w21*g.z + w22*d4.z;
            cf[4*q+3] += w11*a.w + w12*e.w + w21*g.w + w22*d4.w;
        }
    }

    float net[DD];
    #pragma unroll
    for (int j = 0; j < DD; ++j)
        net[j] = fc_p_b[j] + px*fc_p_W[j] + py*fc_p_W[DD+j] + pz*fc_p_W[2*DD+j] + cf[j];

    for (int s = 0; s < 5; ++s) {
        if (s > 0) {
            #pragma unroll
            for (int j = 0; j < DD; ++j) net[j] += cf[j];
        }
        const float* w0 = W0 + (size_t)s * DD * DD;
        const float* w1 = W1 + (size_t)s * DD * DD;
        float h[DD];
        #pragma unroll
        for (int j = 0; j < DD; ++j) h[j] = b0[s * DD + j];
        #pragma unroll 4
        for (int k = 0; k < DD; ++k) {
            const float xk = fmaxf(net[k], 0.0f);
            #pragma unroll
            for (int j = 0; j < DD; ++j) h[j] += xk * w0[k * DD + j];
        }
        #pragma unroll
        for (int j = 0; j < DD; ++j) net[j] += b1[s * DD + j];
        #pragma unroll 4
        for (int k = 0; k < DD; ++k) {
            const float hk = fmaxf(h[k], 0.0f);
            #pragma unroll
            for (int j = 0; j < DD; ++j) net[j] += hk * w1[k * DD + j];
        }
    }

    float o = fc_out_b[0];
    #pragma unroll
    for (int k = 0; k < DD; ++k) o += fmaxf(net[k], 0.0f) * fc_out_W[k];
    out[t] = o;
}

extern "C" void kernel_launch(void* const* d_in, const int* in_sizes, int n_in,
                              void* d_out, int out_size, void* d_ws, size_t ws_size,
                              hipStream_t stream) {
    const float* p        = (const float*)d_in[0];
    // d_in[1] = z  [B,128]  -- unused by the reference
    const float* c        = (const float*)d_in[2];
    const float* Cmat     = (const float*)d_in[3];
    const float* fc_p_W   = (const float*)d_in[4];
    const float* fc_p_b   = (const float*)d_in[5];
    const float* W0       = (const float*)d_in[6];
    const float* b0       = (const float*)d_in[7];
    const float* W1       = (const float*)d_in[8];
    const float* b1       = (const float*)d_in[9];
    const float* fc_out_W = (const float*)d_in[10];
    const float* fc_out_b = (const float*)d_in[11];
    float* out = (float*)d_out;

    const size_t cf_bytes = (size_t)NPT * DD * 4;   // 8 MiB

    if (ws_size >= cf_bytes) {
        float* cf_ws = (float*)d_ws;
        gather_kernel<<<(NPT * 8) / 256, 256, 0, stream>>>(p, c, Cmat, (float4*)cf_ws);
        mlp_kernel<<<NPT / 256, 256, 0, stream>>>(p, cf_ws, fc_p_W, fc_p_b,
                                                  W0, b0, W1, b1, fc_out_W, fc_out_b, out);
    } else {
        decoder_fused_kernel<<<NPT / 256, 256, 0, stream>>>(p, c, Cmat, fc_p_W, fc_p_b,
                                                            W0, b0, W1, b1, fc_out_W, fc_out_b, out);
    }
}